// Round 13
// baseline (1138.870 us; speedup 1.0000x reference)
//
#include <hip/hip_runtime.h>
#include <math.h>

#define B_ 8
#define N_ 2048
#define C_ 256
#define TOK (B_*N_)
#define T_ 64
#define NCH (N_/T_)   // 32 chunks per batch

struct GArgs {
  const float* W[6];
  const float* bias[6];
  float* outQ; float* outK; float* outV; float* outA; float* outB; float* outO;
};

__device__ __forceinline__ float dot4(const float4& a, const float4& b) {
  return (a.x*b.x + a.y*b.y) + (a.z*b.z + a.w*b.w);
}
__device__ __forceinline__ float rdlane(float x, int idx) {
  return __int_as_float(__builtin_amdgcn_readlane(__float_as_int(x), idx));
}

// ---------------- Tiled f32 GEMM with fused epilogues (unchanged) ----------
__global__ __launch_bounds__(256) void gemm_multi(const float* __restrict__ X,
                                                  int pbase, GArgs ga) {
  const int p = pbase + blockIdx.y;
  const float* __restrict__ Wp = ga.W[p];
  const float* __restrict__ bp = ga.bias[p];
  const int rowBase = blockIdx.x * 64;
  const int tid = threadIdx.x;
  const int tx = tid & 15;
  const int ty = tid >> 4;

  __shared__ float xs[64][33];
  __shared__ float wsm[256][33];

  float acc[4][16];
  #pragma unroll
  for (int r = 0; r < 4; ++r)
    #pragma unroll
    for (int c = 0; c < 16; ++c) acc[r][c] = bp[tx + 16*c];

  for (int k0 = 0; k0 < C_; k0 += 32) {
    #pragma unroll
    for (int pass = 0; pass < 2; ++pass) {
      int flat = (pass*256 + tid) * 4;
      int r = flat >> 5, kk = flat & 31;
      const float4 v = *(const float4*)(X + (size_t)(rowBase + r)*C_ + k0 + kk);
      xs[r][kk] = v.x; xs[r][kk+1] = v.y; xs[r][kk+2] = v.z; xs[r][kk+3] = v.w;
    }
    #pragma unroll
    for (int pass = 0; pass < 8; ++pass) {
      int flat = (pass*256 + tid) * 4;
      int c = flat >> 5, kk = flat & 31;
      const float4 v = *(const float4*)(Wp + (size_t)c*C_ + k0 + kk);
      wsm[c][kk] = v.x; wsm[c][kk+1] = v.y; wsm[c][kk+2] = v.z; wsm[c][kk+3] = v.w;
    }
    __syncthreads();
    #pragma unroll
    for (int kk = 0; kk < 32; ++kk) {
      float xr[4];
      #pragma unroll
      for (int r = 0; r < 4; ++r) xr[r] = xs[ty*4 + r][kk];
      #pragma unroll
      for (int c = 0; c < 16; ++c) {
        float wv = wsm[tx + 16*c][kk];
        #pragma unroll
        for (int r = 0; r < 4; ++r) acc[r][c] += xr[r] * wv;
      }
    }
    __syncthreads();
  }

  if (p <= 2) {
    float part[4] = {0.f, 0.f, 0.f, 0.f};
    #pragma unroll
    for (int r = 0; r < 4; ++r)
      #pragma unroll
      for (int c = 0; c < 16; ++c) {
        float y = acc[r][c];
        float s = y / (1.f + __expf(-y));
        acc[r][c] = s;
        part[r] += s * s;
      }
    float* outp = (p == 0) ? ga.outQ : (p == 1) ? ga.outK : ga.outV;
    if (p == 2) {
      #pragma unroll
      for (int r = 0; r < 4; ++r)
        #pragma unroll
        for (int c = 0; c < 16; ++c)
          outp[(size_t)(rowBase + ty*4 + r)*C_ + tx + 16*c] = acc[r][c];
    } else {
      __syncthreads();
      float* red = &xs[0][0];
      float* rnorm = &wsm[0][0];
      #pragma unroll
      for (int r = 0; r < 4; ++r) red[(ty*4 + r)*17 + tx] = part[r];
      __syncthreads();
      if (tid < 64) {
        float s = 0.f;
        #pragma unroll
        for (int i = 0; i < 16; ++i) s += red[tid*17 + i];
        rnorm[tid] = 1.f / (sqrtf(s) + 1e-6f);
      }
      __syncthreads();
      #pragma unroll
      for (int r = 0; r < 4; ++r) {
        float sc = rnorm[ty*4 + r];
        #pragma unroll
        for (int c = 0; c < 16; ++c)
          outp[(size_t)(rowBase + ty*4 + r)*C_ + tx + 16*c] = acc[r][c] * sc;
      }
    }
  } else if (p <= 4) {
    float part[4] = {0.f, 0.f, 0.f, 0.f};
    #pragma unroll
    for (int r = 0; r < 4; ++r)
      #pragma unroll
      for (int c = 0; c < 16; ++c) {
        float y = acc[r][c];
        part[r] += 1.f / (1.f + __expf(-y));
      }
    __syncthreads();
    float* red = &xs[0][0];
    #pragma unroll
    for (int r = 0; r < 4; ++r) red[(ty*4 + r)*17 + tx] = part[r];
    __syncthreads();
    if (tid < 64) {
      float s = 0.f;
      #pragma unroll
      for (int i = 0; i < 16; ++i) s += red[tid*17 + i];
      ((p == 3) ? ga.outA : ga.outB)[rowBase + tid] = s * (1.f / 256.f);
    }
  } else {
    #pragma unroll
    for (int r = 0; r < 4; ++r)
      #pragma unroll
      for (int c = 0; c < 16; ++c)
        ga.outO[(size_t)(rowBase + ty*4 + r)*C_ + tx + 16*c] = acc[r][c];
  }
}

// ---------------- fused gram + WY solves + intra output --------------------
// R12 math; perf restructure:
//  - U stored ROW-MAJOR coalesced inside the solve loop (scan wants rows).
//  - Qtilde: runtime t-loop, streams straight to qrm (row-major, separate
//    buffer) -> no qt_ register array, no barrier, small code.
//  - O_intra: runtime t-loop (y_ inner indices static).
//  - Solves keep full unroll (required for register-static u_/y_).
__global__ __launch_bounds__(256) void chunk_prep(const float* __restrict__ kn,
                                                  const float* __restrict__ qn,
                                                  float* __restrict__ vO,
                                                  const float* __restrict__ Ag,
                                                  const float* __restrict__ Bg,
                                                  float* __restrict__ Ubuf,
                                                  float* __restrict__ qrm,
                                                  float* __restrict__ gbuf,
                                                  float* __restrict__ Oout) {
  __shared__ float Gl[64][68];
  __shared__ float Wl[64][68];
  __shared__ float Kp[4096];   // 64 rows x 16 swizzled 16B units
  __shared__ float Qp[4096];
  __shared__ float gam[64], al[64], bl[64];
  const int bid = blockIdx.x;
  const int b = bid & 7, c = bid >> 3;
  const size_t ct0 = (size_t)b*N_ + (size_t)c*T_;
  const size_t base = ct0 * C_;
  const int tid = threadIdx.x;
  const int lane = tid & 63;   // row index in gram
  const int sg = tid >> 6;     // column group

  if (tid < 64) { al[tid] = Ag[ct0 + tid]; bl[tid] = Bg[ct0 + tid]; }

  // ---- gram over 4 k-panels (swizzled staging) ----
  float accG[16], accQ[16];
  #pragma unroll
  for (int m = 0; m < 16; ++m) { accG[m] = 0.f; accQ[m] = 0.f; }
  for (int p = 0; p < 4; ++p) {
    __syncthreads();
    #pragma unroll
    for (int i = 0; i < 4; ++i) {
      int idx = i*256 + tid;            // 1024 float4 units
      int t = idx >> 4, u = idx & 15;
      int phys = (t*16 + (u ^ (t & 15))) * 4;
      *(float4*)&Kp[phys] = *(const float4*)(kn + base + (size_t)t*C_ + p*64 + u*4);
      *(float4*)&Qp[phys] = *(const float4*)(qn + base + (size_t)t*C_ + p*64 + u*4);
    }
    __syncthreads();
    #pragma unroll 4
    for (int j4 = 0; j4 < 16; ++j4) {
      float4 kt = *(const float4*)&Kp[(lane*16 + (j4 ^ (lane & 15))) * 4];
      float4 qt = *(const float4*)&Qp[(lane*16 + (j4 ^ (lane & 15))) * 4];
      #pragma unroll
      for (int m = 0; m < 16; ++m) {
        int r = sg*16 + m;
        float4 ks = *(const float4*)&Kp[(r*16 + (j4 ^ (r & 15))) * 4];  // uniform bcast
        accG[m] += dot4(kt, ks);
        accQ[m] += dot4(qt, ks);
      }
    }
  }
  __syncthreads();
  #pragma unroll
  for (int m = 0; m < 16; ++m) {
    int col = sg*16 + m;
    Gl[lane][col] = (col <  lane) ? accG[m] : 0.f;  // strict lower
    Wl[lane][col] = (col <= lane) ? accQ[m] : 0.f;  // lower incl diag
  }
  __syncthreads();
  if (tid == 0) {
    float g = 1.f;
    for (int s = 0; s < 64; ++s) { g *= al[s]; gam[s] = g; }
  }
  __syncthreads();
  if (tid < 64) gbuf[ct0 + tid] = gam[tid];

  const int j = tid;  // column 0..255

  // ---- U solve (registers, static indices; row-major coalesced store) ----
  float u_[64];
  #pragma unroll
  for (int i = 0; i < 64; ++i) u_[i] = 0.f;
  #pragma unroll 64
  for (int s = 0; s < 64; ++s) {
    float acc = kn[base + (size_t)s*C_ + j];
    #pragma unroll
    for (int r4 = 0; r4 <= (s >> 2); ++r4) {
      float4 g = *(const float4*)&Gl[s][r4*4];
      acc -= g.x*u_[r4*4] + g.y*u_[r4*4+1] + g.z*u_[r4*4+2] + g.w*u_[r4*4+3];
    }
    u_[s] = bl[s] * acc;
    Ubuf[base + (size_t)s*C_ + j] = u_[s];     // coalesced row store
  }

  // ---- Qtilde: runtime t loop, stream to qrm (row-major) ----
  for (int t = 0; t < 64; ++t) {
    float acc = qn[base + (size_t)t*C_ + j];
    #pragma unroll
    for (int s4 = 0; s4 < 16; ++s4) {
      float4 w = *(const float4*)&Wl[t][s4*4];
      acc -= w.x*u_[s4*4] + w.y*u_[s4*4+1] + w.z*u_[s4*4+2] + w.w*u_[s4*4+3];
    }
    qrm[base + (size_t)t*C_ + j] = acc;        // coalesced row store
  }

  // ---- scale: Gl -> Ghat, Wl -> Omega ----
  __syncthreads();
  #pragma unroll
  for (int p2 = 0; p2 < 16; ++p2) {
    int idx = p2*256 + tid; int s = idx >> 6, r = idx & 63;
    float rs = gam[s] / gam[r];
    Gl[s][r] *= rs;
    Wl[s][r] *= rs;
  }
  __syncthreads();
  const float gT = gam[63];
  // ---- Y solve ----
  float y_[64];
  #pragma unroll
  for (int i = 0; i < 64; ++i) y_[i] = 0.f;
  #pragma unroll 64
  for (int s = 0; s < 64; ++s) {
    float acc = vO[base + (size_t)s*C_ + j];
    #pragma unroll
    for (int r4 = 0; r4 <= (s >> 2); ++r4) {
      float4 g = *(const float4*)&Gl[s][r4*4];
      acc -= g.x*y_[r4*4] + g.y*y_[r4*4+1] + g.z*y_[r4*4+2] + g.w*y_[r4*4+3];
    }
    y_[s] = bl[s] * acc;
  }
  __syncthreads();   // all vO chunk reads done
  #pragma unroll
  for (int s4 = 0; s4 < 16; ++s4) {
    float z0 = (gT / gam[s4*4+0]) * y_[s4*4+0];
    float z1 = (gT / gam[s4*4+1]) * y_[s4*4+1];
    float z2 = (gT / gam[s4*4+2]) * y_[s4*4+2];
    float z3 = (gT / gam[s4*4+3]) * y_[s4*4+3];
    *(float4*)&vO[base + (size_t)j*64 + s4*4] = make_float4(z0, z1, z2, z3);  // Z^T [i][s]
  }
  // ---- O_intra = Omega * y (runtime t loop) ----
  for (int t = 0; t < 64; ++t) {
    float acc = 0.f;
    #pragma unroll
    for (int s4 = 0; s4 < 16; ++s4) {
      float4 w = *(const float4*)&Wl[t][s4*4];
      acc += w.x*y_[s4*4] + w.y*y_[s4*4+1] + w.z*y_[s4*4+2] + w.w*y_[s4*4+3];
    }
    Oout[base + (size_t)t*C_ + j] = acc;
  }
}

// ---------------- serial chunk scan (swizzled row-major LDS, b128) ---------
// grid 256 = (b = bid&7, wgrp = bid>>3); 4 waves x 2 S-rows.
// Q~ and U staged ROW-MAJOR with 16B XOR swizzle (unit ^= t&15): Pass A+B
// reads ONE ds_read_b128 per tile per j4 (was 8 ds_read_b32) -- scan was
// LDS-instruction-throughput bound. Pass C restages K over Qs (linear).
__global__ __launch_bounds__(256) void chunk_scan(const float* __restrict__ kn,
                                                  const float* __restrict__ qrm,
                                                  const float* __restrict__ urm,
                                                  const float* __restrict__ ztT,
                                                  const float* __restrict__ gbuf,
                                                  float* __restrict__ Oout) {
  __shared__ float Qs[16384];   // swizzled Q~ rows, later linear K
  __shared__ float Us[16384];   // swizzled U rows
  const int bid = blockIdx.x;
  const int b = bid & 7;
  const int wgrp = bid >> 3;
  const int tid = threadIdx.x;
  const int wave = tid >> 6, lane = tid & 63;
  const int i0 = wgrp*8 + wave*2;
  const int lx = lane & 15;     // swizzle key for this lane's row

  float4 S0 = make_float4(0.f,0.f,0.f,0.f);
  float4 S1 = make_float4(0.f,0.f,0.f,0.f);

  for (int ch = 0; ch < NCH; ++ch) {
    const size_t ct0 = (size_t)b*N_ + (size_t)ch*T_;
    const size_t base = ct0 * C_;

    // stage Q~/U row-major with 16B XOR swizzle: unit u of row t -> u^(t&15)
    #pragma unroll
    for (int i = 0; i < 16; ++i) {
      int g = i*256 + tid;            // 4096 16B units
      int t = g >> 6, u = g & 63;
      int phys = (t*64 + (u ^ (t & 15))) * 4;
      *(float4*)&Qs[phys] = *(const float4*)(qrm + base + (size_t)g*4);
      *(float4*)&Us[phys] = *(const float4*)(urm + base + (size_t)g*4);
    }
    __syncthreads();

    const float gv = gbuf[ct0 + lane];
    const float gT = rdlane(gv, 63);

    // fused Pass A+B (lane = t = s): one b128 per tile per j4
    float oA0=0.f, oA1=0.f, dB0=0.f, dB1=0.f;
    #pragma unroll 8
    for (int j4 = 0; j4 < 64; ++j4) {
      float4 qv = *(const float4*)&Qs[(lane*64 + (j4 ^ lx)) * 4];
      float4 uv = *(const float4*)&Us[(lane*64 + (j4 ^ lx)) * 4];
      int jj = j4 ^ lx;               // logical j-group this unit holds
      float sx0 = rdlane(S0.x, jj), sy0 = rdlane(S0.y, jj);
      float sz0 = rdlane(S0.z, jj), sw0 = rdlane(S0.w, jj);
      float sx1 = rdlane(S1.x, jj), sy1 = rdlane(S1.y, jj);
      float sz1 = rdlane(S1.z, jj), sw1 = rdlane(S1.w, jj);
      oA0 += sx0*qv.x + sy0*qv.y + sz0*qv.z + sw0*qv.w;
      oA1 += sx1*qv.x + sy1*qv.y + sz1*qv.z + sw1*qv.w;
      dB0 += sx0*uv.x + sy0*uv.y + sz0*uv.z + sw0*uv.w;
      dB1 += sx1*uv.x + sy1*uv.y + sz1*uv.z + sw1*uv.w;
    }
    // cross-output RMW (O_intra already there)
    float* orow = Oout + base + (size_t)lane*C_ + i0;
    orow[0] += gv*oA0;
    orow[1] += gv*oA1;
    const float z0 = ztT[base + (size_t)i0*64 + lane];
    const float z1 = ztT[base + (size_t)(i0+1)*64 + lane];
    const float cf0 = gT*dB0 - z0;
    const float cf1 = gT*dB1 - z1;
    __syncthreads();          // A/B LDS reads done

    // re-stage K (row-major linear) over the Qs region
    #pragma unroll
    for (int i = 0; i < 16; ++i) {
      int idx = (i*256 + tid) * 4;
      *(float4*)&Qs[idx] = *(const float4*)(kn + base + idx);
    }
    __syncthreads();

    // Pass C: S' = gT*S - sum_s cf[s]*k_s  (lane = col-block, contiguous)
    float4 A0 = make_float4(0.f,0.f,0.f,0.f);
    float4 A1 = make_float4(0.f,0.f,0.f,0.f);
    #pragma unroll 8
    for (int s = 0; s < 64; ++s) {
      float4 kv = *(const float4*)&Qs[s*256 + lane*4];
      float ca = rdlane(cf0, s), cb = rdlane(cf1, s);
      A0.x += ca*kv.x; A0.y += ca*kv.y; A0.z += ca*kv.z; A0.w += ca*kv.w;
      A1.x += cb*kv.x; A1.y += cb*kv.y; A1.z += cb*kv.z; A1.w += cb*kv.w;
    }
    S0.x = gT*S0.x - A0.x; S0.y = gT*S0.y - A0.y;
    S0.z = gT*S0.z - A0.z; S0.w = gT*S0.w - A0.w;
    S1.x = gT*S1.x - A1.x; S1.y = gT*S1.y - A1.y;
    S1.z = gT*S1.z - A1.z; S1.w = gT*S1.w - A1.w;
    __syncthreads();          // C LDS reads done before next staging
  }
}

extern "C" void kernel_launch(void* const* d_in, const int* in_sizes, int n_in,
                              void* d_out, int out_size, void* d_ws, size_t ws_size,
                              hipStream_t stream) {
  const float* x  = (const float*)d_in[0];
  const float* Wq = (const float*)d_in[1];  const float* bq = (const float*)d_in[2];
  const float* Wk = (const float*)d_in[3];  const float* bk = (const float*)d_in[4];
  const float* Wv = (const float*)d_in[5];  const float* bv = (const float*)d_in[6];
  const float* Wa = (const float*)d_in[7];  const float* ba = (const float*)d_in[8];
  const float* Wb = (const float*)d_in[9];  const float* bb = (const float*)d_in[10];
  const float* Wo = (const float*)d_in[11]; const float* bo = (const float*)d_in[12];

  float* ws = (float*)d_ws;
  const size_t TC = (size_t)TOK * C_;
  float* qn   = ws;                    // Q projection (read-only after proj)
  float* kn   = ws + TC;
  float* vO   = ws + 2*TC;             // V -> Z^T [i][s] (in place)
  float* Ag   = ws + 3*TC;
  float* Bg   = Ag + TOK;
  float* gbuf = Bg + TOK;
  float* Ubuf = gbuf + TOK;            // U row-major
  float* qrm  = Ubuf + TC;             // Qtilde row-major

  GArgs ga;
  ga.W[0] = Wq; ga.W[1] = Wk; ga.W[2] = Wv; ga.W[3] = Wa; ga.W[4] = Wb; ga.W[5] = Wo;
  ga.bias[0] = bq; ga.bias[1] = bk; ga.bias[2] = bv; ga.bias[3] = ba; ga.bias[4] = bb; ga.bias[5] = bo;
  ga.outQ = qn; ga.outK = kn; ga.outV = vO; ga.outA = Ag; ga.outB = Bg;
  ga.outO = (float*)d_out;

  gemm_multi<<<dim3(TOK/64, 5), 256, 0, stream>>>(x, 0, ga);
  chunk_prep<<<dim3(256), 256, 0, stream>>>(kn, qn, vO, Ag, Bg, Ubuf, qrm, gbuf,
                                            (float*)d_out);
  chunk_scan<<<dim3(256), 256, 0, stream>>>(kn, qrm, Ubuf, vO, gbuf,
                                            (float*)d_out);
  gemm_multi<<<dim3(TOK/64, 1), 256, 0, stream>>>((float*)d_out, 5, ga);
}

// Round 14
// 764.848 us; speedup vs baseline: 1.4890x; 1.4890x over previous
//
#include <hip/hip_runtime.h>
#include <math.h>

#define B_ 8
#define N_ 2048
#define C_ 256
#define TOK (B_*N_)
#define T_ 64
#define NCH (N_/T_)   // 32 chunks per batch

struct GArgs {
  const float* W[6];
  const float* bias[6];
  float* outQ; float* outK; float* outV; float* outA; float* outB; float* outO;
};

__device__ __forceinline__ float dot4(const float4& a, const float4& b) {
  return (a.x*b.x + a.y*b.y) + (a.z*b.z + a.w*b.w);
}
__device__ __forceinline__ float rdlane(float x, int idx) {
  return __int_as_float(__builtin_amdgcn_readlane(__float_as_int(x), idx));
}

// ---------------- Tiled f32 GEMM with fused epilogues (unchanged) ----------
__global__ __launch_bounds__(256) void gemm_multi(const float* __restrict__ X,
                                                  int pbase, GArgs ga) {
  const int p = pbase + blockIdx.y;
  const float* __restrict__ Wp = ga.W[p];
  const float* __restrict__ bp = ga.bias[p];
  const int rowBase = blockIdx.x * 64;
  const int tid = threadIdx.x;
  const int tx = tid & 15;
  const int ty = tid >> 4;

  __shared__ float xs[64][33];
  __shared__ float wsm[256][33];

  float acc[4][16];
  #pragma unroll
  for (int r = 0; r < 4; ++r)
    #pragma unroll
    for (int c = 0; c < 16; ++c) acc[r][c] = bp[tx + 16*c];

  for (int k0 = 0; k0 < C_; k0 += 32) {
    #pragma unroll
    for (int pass = 0; pass < 2; ++pass) {
      int flat = (pass*256 + tid) * 4;
      int r = flat >> 5, kk = flat & 31;
      const float4 v = *(const float4*)(X + (size_t)(rowBase + r)*C_ + k0 + kk);
      xs[r][kk] = v.x; xs[r][kk+1] = v.y; xs[r][kk+2] = v.z; xs[r][kk+3] = v.w;
    }
    #pragma unroll
    for (int pass = 0; pass < 8; ++pass) {
      int flat = (pass*256 + tid) * 4;
      int c = flat >> 5, kk = flat & 31;
      const float4 v = *(const float4*)(Wp + (size_t)c*C_ + k0 + kk);
      wsm[c][kk] = v.x; wsm[c][kk+1] = v.y; wsm[c][kk+2] = v.z; wsm[c][kk+3] = v.w;
    }
    __syncthreads();
    #pragma unroll
    for (int kk = 0; kk < 32; ++kk) {
      float xr[4];
      #pragma unroll
      for (int r = 0; r < 4; ++r) xr[r] = xs[ty*4 + r][kk];
      #pragma unroll
      for (int c = 0; c < 16; ++c) {
        float wv = wsm[tx + 16*c][kk];
        #pragma unroll
        for (int r = 0; r < 4; ++r) acc[r][c] += xr[r] * wv;
      }
    }
    __syncthreads();
  }

  if (p <= 2) {
    float part[4] = {0.f, 0.f, 0.f, 0.f};
    #pragma unroll
    for (int r = 0; r < 4; ++r)
      #pragma unroll
      for (int c = 0; c < 16; ++c) {
        float y = acc[r][c];
        float s = y / (1.f + __expf(-y));
        acc[r][c] = s;
        part[r] += s * s;
      }
    float* outp = (p == 0) ? ga.outQ : (p == 1) ? ga.outK : ga.outV;
    if (p == 2) {
      #pragma unroll
      for (int r = 0; r < 4; ++r)
        #pragma unroll
        for (int c = 0; c < 16; ++c)
          outp[(size_t)(rowBase + ty*4 + r)*C_ + tx + 16*c] = acc[r][c];
    } else {
      __syncthreads();
      float* red = &xs[0][0];
      float* rnorm = &wsm[0][0];
      #pragma unroll
      for (int r = 0; r < 4; ++r) red[(ty*4 + r)*17 + tx] = part[r];
      __syncthreads();
      if (tid < 64) {
        float s = 0.f;
        #pragma unroll
        for (int i = 0; i < 16; ++i) s += red[tid*17 + i];
        rnorm[tid] = 1.f / (sqrtf(s) + 1e-6f);
      }
      __syncthreads();
      #pragma unroll
      for (int r = 0; r < 4; ++r) {
        float sc = rnorm[ty*4 + r];
        #pragma unroll
        for (int c = 0; c < 16; ++c)
          outp[(size_t)(rowBase + ty*4 + r)*C_ + tx + 16*c] = acc[r][c] * sc;
      }
    }
  } else if (p <= 4) {
    float part[4] = {0.f, 0.f, 0.f, 0.f};
    #pragma unroll
    for (int r = 0; r < 4; ++r)
      #pragma unroll
      for (int c = 0; c < 16; ++c) {
        float y = acc[r][c];
        part[r] += 1.f / (1.f + __expf(-y));
      }
    __syncthreads();
    float* red = &xs[0][0];
    #pragma unroll
    for (int r = 0; r < 4; ++r) red[(ty*4 + r)*17 + tx] = part[r];
    __syncthreads();
    if (tid < 64) {
      float s = 0.f;
      #pragma unroll
      for (int i = 0; i < 16; ++i) s += red[tid*17 + i];
      ((p == 3) ? ga.outA : ga.outB)[rowBase + tid] = s * (1.f / 256.f);
    }
  } else {
    #pragma unroll
    for (int r = 0; r < 4; ++r)
      #pragma unroll
      for (int c = 0; c < 16; ++c)
        ga.outO[(size_t)(rowBase + ty*4 + r)*C_ + tx + 16*c] = acc[r][c];
  }
}

// ---------------- fused gram + WY solves + intra output --------------------
// R12 math; structural fix: per-thread u/y state lives in a PADDED LDS pool
// (row j at pool+j*68, b128 reads conflict-free), not in 64-float register
// arrays (which spilled to scratch -> 454MB write traffic, R13). All solve /
// Qtilde / O_intra loops are runtime-indexed (small code, no I-cache blow).
// Pool is reused: gram stages swizzled Kp/Qp in it first.
__global__ __launch_bounds__(256) void chunk_prep(const float* __restrict__ kn,
                                                  const float* __restrict__ qn,
                                                  float* __restrict__ vO,
                                                  const float* __restrict__ Ag,
                                                  const float* __restrict__ Bg,
                                                  float* __restrict__ Ubuf,
                                                  float* __restrict__ qrm,
                                                  float* __restrict__ gbuf,
                                                  float* __restrict__ Oout) {
  __shared__ float Gl[64][68];
  __shared__ float Wl[64][68];
  __shared__ float pool[17408];       // gram: Kp[0:4096]+Qp[4096:8192]; solves: UY rows [j*68]
  __shared__ float gam[64], al[64], bl[64];
  float* Kp = pool;
  float* Qp = pool + 4096;
  const int bid = blockIdx.x;
  const int b = bid & 7, c = bid >> 3;
  const size_t ct0 = (size_t)b*N_ + (size_t)c*T_;
  const size_t base = ct0 * C_;
  const int tid = threadIdx.x;
  const int lane = tid & 63;   // row index in gram
  const int sg = tid >> 6;     // column group

  if (tid < 64) { al[tid] = Ag[ct0 + tid]; bl[tid] = Bg[ct0 + tid]; }

  // ---- gram over 4 k-panels (swizzled staging, R12 form) ----
  float accG[16], accQ[16];
  #pragma unroll
  for (int m = 0; m < 16; ++m) { accG[m] = 0.f; accQ[m] = 0.f; }
  for (int p = 0; p < 4; ++p) {
    __syncthreads();
    #pragma unroll
    for (int i = 0; i < 4; ++i) {
      int idx = i*256 + tid;            // 1024 float4 units
      int t = idx >> 4, u = idx & 15;
      int phys = (t*16 + (u ^ (t & 15))) * 4;
      *(float4*)&Kp[phys] = *(const float4*)(kn + base + (size_t)t*C_ + p*64 + u*4);
      *(float4*)&Qp[phys] = *(const float4*)(qn + base + (size_t)t*C_ + p*64 + u*4);
    }
    __syncthreads();
    #pragma unroll 4
    for (int j4 = 0; j4 < 16; ++j4) {
      float4 kt = *(const float4*)&Kp[(lane*16 + (j4 ^ (lane & 15))) * 4];
      float4 qt = *(const float4*)&Qp[(lane*16 + (j4 ^ (lane & 15))) * 4];
      #pragma unroll
      for (int m = 0; m < 16; ++m) {
        int r = sg*16 + m;
        float4 ks = *(const float4*)&Kp[(r*16 + (j4 ^ (r & 15))) * 4];  // uniform bcast
        accG[m] += dot4(kt, ks);
        accQ[m] += dot4(qt, ks);
      }
    }
  }
  __syncthreads();
  #pragma unroll
  for (int m = 0; m < 16; ++m) {
    int col = sg*16 + m;
    Gl[lane][col] = (col <  lane) ? accG[m] : 0.f;  // strict lower
    Wl[lane][col] = (col <= lane) ? accQ[m] : 0.f;  // lower incl diag
  }
  __syncthreads();
  if (tid == 0) {
    float g = 1.f;
    for (int s = 0; s < 64; ++s) { g *= al[s]; gam[s] = g; }
  }
  __syncthreads();
  if (tid < 64) gbuf[ct0 + tid] = gam[tid];
  __syncthreads();   // gram reads of pool done before UY overwrites it

  const int j = tid;            // column 0..255
  float* const myrow = &pool[j * 68];

  // ---- U solve (state in LDS row; runtime loops) ----
  for (int s = 0; s < 64; ++s) {
    float a0 = kn[base + (size_t)s*C_ + j], a1 = 0.f, a2 = 0.f, a3 = 0.f;
    for (int r4 = 0; r4 <= (s >> 2); ++r4) {
      float4 g = *(const float4*)&Gl[s][r4*4];     // wave-uniform bcast
      float4 uu = *(const float4*)&myrow[r4*4];    // conflict-free b128
      a0 -= g.x*uu.x; a1 -= g.y*uu.y; a2 -= g.z*uu.z; a3 -= g.w*uu.w;
    }
    float us = bl[s] * ((a0 + a1) + (a2 + a3));
    myrow[s] = us;
    Ubuf[base + (size_t)s*C_ + j] = us;            // coalesced row store
  }

  // ---- Qtilde: runtime t loop, stream to qrm (row-major) ----
  for (int t = 0; t < 64; ++t) {
    float a0 = qn[base + (size_t)t*C_ + j], a1 = 0.f, a2 = 0.f, a3 = 0.f;
    for (int s4 = 0; s4 < 16; ++s4) {
      float4 w = *(const float4*)&Wl[t][s4*4];
      float4 uu = *(const float4*)&myrow[s4*4];
      a0 -= w.x*uu.x; a1 -= w.y*uu.y; a2 -= w.z*uu.z; a3 -= w.w*uu.w;
    }
    qrm[base + (size_t)t*C_ + j] = (a0 + a1) + (a2 + a3);
  }

  // ---- scale: Gl -> Ghat, Wl -> Omega ----
  __syncthreads();
  #pragma unroll
  for (int p2 = 0; p2 < 16; ++p2) {
    int idx = p2*256 + tid; int s = idx >> 6, r = idx & 63;
    float rs = gam[s] / gam[r];
    Gl[s][r] *= rs;
    Wl[s][r] *= rs;
  }
  __syncthreads();
  const float gT = gam[63];

  // ---- Y solve (reuses myrow; u no longer needed) ----
  for (int s = 0; s < 64; ++s) {
    float a0 = vO[base + (size_t)s*C_ + j], a1 = 0.f, a2 = 0.f, a3 = 0.f;
    for (int r4 = 0; r4 <= (s >> 2); ++r4) {
      float4 g = *(const float4*)&Gl[s][r4*4];
      float4 yy = *(const float4*)&myrow[r4*4];
      a0 -= g.x*yy.x; a1 -= g.y*yy.y; a2 -= g.z*yy.z; a3 -= g.w*yy.w;
    }
    myrow[s] = bl[s] * ((a0 + a1) + (a2 + a3));
  }
  __syncthreads();   // all vO chunk reads done (also y rows complete)
  for (int s4 = 0; s4 < 16; ++s4) {
    float4 yy = *(const float4*)&myrow[s4*4];
    float z0 = (gT / gam[s4*4+0]) * yy.x;
    float z1 = (gT / gam[s4*4+1]) * yy.y;
    float z2 = (gT / gam[s4*4+2]) * yy.z;
    float z3 = (gT / gam[s4*4+3]) * yy.w;
    *(float4*)&vO[base + (size_t)j*64 + s4*4] = make_float4(z0, z1, z2, z3);  // Z^T [i][s]
  }
  // ---- O_intra = Omega * y (runtime t loop) ----
  for (int t = 0; t < 64; ++t) {
    float a0 = 0.f, a1 = 0.f, a2 = 0.f, a3 = 0.f;
    for (int s4 = 0; s4 < 16; ++s4) {
      float4 w = *(const float4*)&Wl[t][s4*4];
      float4 yy = *(const float4*)&myrow[s4*4];
      a0 += w.x*yy.x; a1 += w.y*yy.y; a2 += w.z*yy.z; a3 += w.w*yy.w;
    }
    Oout[base + (size_t)t*C_ + j] = (a0 + a1) + (a2 + a3);
  }
}

// ---------------- serial chunk scan (swizzled b128 LDS, uniform readlane) --
// grid 256 = (b = bid&7, wgrp = bid>>3); 4 waves x 2 S-rows.
// Q~/U staged row-major with 16B XOR swizzle. Pass A+B iterates LOGICAL j
// (uniform -> readlane is a plain SGPR broadcast, no waterfall); only the
// per-lane LDS ADDRESS is swizzled (j ^ lx). One b128 per tile per j.
__global__ __launch_bounds__(256) void chunk_scan(const float* __restrict__ kn,
                                                  const float* __restrict__ qrm,
                                                  const float* __restrict__ urm,
                                                  const float* __restrict__ ztT,
                                                  const float* __restrict__ gbuf,
                                                  float* __restrict__ Oout) {
  __shared__ float Qs[16384];   // swizzled Q~ rows, later linear K
  __shared__ float Us[16384];   // swizzled U rows
  const int bid = blockIdx.x;
  const int b = bid & 7;
  const int wgrp = bid >> 3;
  const int tid = threadIdx.x;
  const int wave = tid >> 6, lane = tid & 63;
  const int i0 = wgrp*8 + wave*2;
  const int lx = lane & 15;     // swizzle key for this lane's row

  float4 S0 = make_float4(0.f,0.f,0.f,0.f);
  float4 S1 = make_float4(0.f,0.f,0.f,0.f);

  for (int ch = 0; ch < NCH; ++ch) {
    const size_t ct0 = (size_t)b*N_ + (size_t)ch*T_;
    const size_t base = ct0 * C_;

    // stage Q~/U row-major with 16B XOR swizzle: unit u of row t -> u^(t&15)
    #pragma unroll
    for (int i = 0; i < 16; ++i) {
      int g = i*256 + tid;            // 4096 16B units
      int t = g >> 6, u = g & 63;
      int phys = (t*64 + (u ^ (t & 15))) * 4;
      *(float4*)&Qs[phys] = *(const float4*)(qrm + base + (size_t)g*4);
      *(float4*)&Us[phys] = *(const float4*)(urm + base + (size_t)g*4);
    }
    __syncthreads();

    const float gv = gbuf[ct0 + lane];
    const float gT = rdlane(gv, 63);

    // fused Pass A+B (lane = t = s): logical j uniform; address swizzled
    float oA0=0.f, oA1=0.f, dB0=0.f, dB1=0.f;
    #pragma unroll 8
    for (int j = 0; j < 64; ++j) {
      float4 qv = *(const float4*)&Qs[(lane*64 + (j ^ lx)) * 4];
      float4 uv = *(const float4*)&Us[(lane*64 + (j ^ lx)) * 4];
      float sx0 = rdlane(S0.x, j), sy0 = rdlane(S0.y, j);
      float sz0 = rdlane(S0.z, j), sw0 = rdlane(S0.w, j);
      float sx1 = rdlane(S1.x, j), sy1 = rdlane(S1.y, j);
      float sz1 = rdlane(S1.z, j), sw1 = rdlane(S1.w, j);
      oA0 += sx0*qv.x + sy0*qv.y + sz0*qv.z + sw0*qv.w;
      oA1 += sx1*qv.x + sy1*qv.y + sz1*qv.z + sw1*qv.w;
      dB0 += sx0*uv.x + sy0*uv.y + sz0*uv.z + sw0*uv.w;
      dB1 += sx1*uv.x + sy1*uv.y + sz1*uv.z + sw1*uv.w;
    }
    // cross-output RMW (O_intra already there)
    float* orow = Oout + base + (size_t)lane*C_ + i0;
    orow[0] += gv*oA0;
    orow[1] += gv*oA1;
    const float z0 = ztT[base + (size_t)i0*64 + lane];
    const float z1 = ztT[base + (size_t)(i0+1)*64 + lane];
    const float cf0 = gT*dB0 - z0;
    const float cf1 = gT*dB1 - z1;
    __syncthreads();          // A/B LDS reads done

    // re-stage K (row-major linear) over the Qs region
    #pragma unroll
    for (int i = 0; i < 16; ++i) {
      int idx = (i*256 + tid) * 4;
      *(float4*)&Qs[idx] = *(const float4*)(kn + base + idx);
    }
    __syncthreads();

    // Pass C: S' = gT*S - sum_s cf[s]*k_s  (lane = col-block, contiguous)
    float4 A0 = make_float4(0.f,0.f,0.f,0.f);
    float4 A1 = make_float4(0.f,0.f,0.f,0.f);
    #pragma unroll 8
    for (int s = 0; s < 64; ++s) {
      float4 kv = *(const float4*)&Qs[s*256 + lane*4];
      float ca = rdlane(cf0, s), cb = rdlane(cf1, s);
      A0.x += ca*kv.x; A0.y += ca*kv.y; A0.z += ca*kv.z; A0.w += ca*kv.w;
      A1.x += cb*kv.x; A1.y += cb*kv.y; A1.z += cb*kv.z; A1.w += cb*kv.w;
    }
    S0.x = gT*S0.x - A0.x; S0.y = gT*S0.y - A0.y;
    S0.z = gT*S0.z - A0.z; S0.w = gT*S0.w - A0.w;
    S1.x = gT*S1.x - A1.x; S1.y = gT*S1.y - A1.y;
    S1.z = gT*S1.z - A1.z; S1.w = gT*S1.w - A1.w;
    __syncthreads();          // C LDS reads done before next staging
  }
}

extern "C" void kernel_launch(void* const* d_in, const int* in_sizes, int n_in,
                              void* d_out, int out_size, void* d_ws, size_t ws_size,
                              hipStream_t stream) {
  const float* x  = (const float*)d_in[0];
  const float* Wq = (const float*)d_in[1];  const float* bq = (const float*)d_in[2];
  const float* Wk = (const float*)d_in[3];  const float* bk = (const float*)d_in[4];
  const float* Wv = (const float*)d_in[5];  const float* bv = (const float*)d_in[6];
  const float* Wa = (const float*)d_in[7];  const float* ba = (const float*)d_in[8];
  const float* Wb = (const float*)d_in[9];  const float* bb = (const float*)d_in[10];
  const float* Wo = (const float*)d_in[11]; const float* bo = (const float*)d_in[12];

  float* ws = (float*)d_ws;
  const size_t TC = (size_t)TOK * C_;
  float* qn   = ws;                    // Q projection (read-only after proj)
  float* kn   = ws + TC;
  float* vO   = ws + 2*TC;             // V -> Z^T [i][s] (in place)
  float* Ag   = ws + 3*TC;
  float* Bg   = Ag + TOK;
  float* gbuf = Bg + TOK;
  float* Ubuf = gbuf + TOK;            // U row-major
  float* qrm  = Ubuf + TC;             // Qtilde row-major

  GArgs ga;
  ga.W[0] = Wq; ga.W[1] = Wk; ga.W[2] = Wv; ga.W[3] = Wa; ga.W[4] = Wb; ga.W[5] = Wo;
  ga.bias[0] = bq; ga.bias[1] = bk; ga.bias[2] = bv; ga.bias[3] = ba; ga.bias[4] = bb; ga.bias[5] = bo;
  ga.outQ = qn; ga.outK = kn; ga.outV = vO; ga.outA = Ag; ga.outB = Bg;
  ga.outO = (float*)d_out;

  gemm_multi<<<dim3(TOK/64, 5), 256, 0, stream>>>(x, 0, ga);
  chunk_prep<<<dim3(256), 256, 0, stream>>>(kn, qn, vO, Ag, Bg, Ubuf, qrm, gbuf,
                                            (float*)d_out);
  chunk_scan<<<dim3(256), 256, 0, stream>>>(kn, qrm, Ubuf, vO, gbuf,
                                            (float*)d_out);
  gemm_multi<<<dim3(TOK/64, 1), 256, 0, stream>>>((float*)d_out, 5, ga);
}

// Round 15
// 744.474 us; speedup vs baseline: 1.5298x; 1.0274x over previous
//
#include <hip/hip_runtime.h>
#include <math.h>

#define B_ 8
#define N_ 2048
#define C_ 256
#define TOK (B_*N_)
#define T_ 64
#define NCH (N_/T_)   // 32 chunks per batch

struct GArgs {
  const float* W[6];
  const float* bias[6];
  float* outQ; float* outK; float* outV; float* outA; float* outB; float* outO;
};

__device__ __forceinline__ float dot4(const float4& a, const float4& b) {
  return (a.x*b.x + a.y*b.y) + (a.z*b.z + a.w*b.w);
}
__device__ __forceinline__ float rdlane(float x, int idx) {
  return __int_as_float(__builtin_amdgcn_readlane(__float_as_int(x), idx));
}

// ---------------- Tiled f32 GEMM with fused epilogues (unchanged) ----------
__global__ __launch_bounds__(256) void gemm_multi(const float* __restrict__ X,
                                                  int pbase, GArgs ga) {
  const int p = pbase + blockIdx.y;
  const float* __restrict__ Wp = ga.W[p];
  const float* __restrict__ bp = ga.bias[p];
  const int rowBase = blockIdx.x * 64;
  const int tid = threadIdx.x;
  const int tx = tid & 15;
  const int ty = tid >> 4;

  __shared__ float xs[64][33];
  __shared__ float wsm[256][33];

  float acc[4][16];
  #pragma unroll
  for (int r = 0; r < 4; ++r)
    #pragma unroll
    for (int c = 0; c < 16; ++c) acc[r][c] = bp[tx + 16*c];

  for (int k0 = 0; k0 < C_; k0 += 32) {
    #pragma unroll
    for (int pass = 0; pass < 2; ++pass) {
      int flat = (pass*256 + tid) * 4;
      int r = flat >> 5, kk = flat & 31;
      const float4 v = *(const float4*)(X + (size_t)(rowBase + r)*C_ + k0 + kk);
      xs[r][kk] = v.x; xs[r][kk+1] = v.y; xs[r][kk+2] = v.z; xs[r][kk+3] = v.w;
    }
    #pragma unroll
    for (int pass = 0; pass < 8; ++pass) {
      int flat = (pass*256 + tid) * 4;
      int c = flat >> 5, kk = flat & 31;
      const float4 v = *(const float4*)(Wp + (size_t)c*C_ + k0 + kk);
      wsm[c][kk] = v.x; wsm[c][kk+1] = v.y; wsm[c][kk+2] = v.z; wsm[c][kk+3] = v.w;
    }
    __syncthreads();
    #pragma unroll
    for (int kk = 0; kk < 32; ++kk) {
      float xr[4];
      #pragma unroll
      for (int r = 0; r < 4; ++r) xr[r] = xs[ty*4 + r][kk];
      #pragma unroll
      for (int c = 0; c < 16; ++c) {
        float wv = wsm[tx + 16*c][kk];
        #pragma unroll
        for (int r = 0; r < 4; ++r) acc[r][c] += xr[r] * wv;
      }
    }
    __syncthreads();
  }

  if (p <= 2) {
    float part[4] = {0.f, 0.f, 0.f, 0.f};
    #pragma unroll
    for (int r = 0; r < 4; ++r)
      #pragma unroll
      for (int c = 0; c < 16; ++c) {
        float y = acc[r][c];
        float s = y / (1.f + __expf(-y));
        acc[r][c] = s;
        part[r] += s * s;
      }
    float* outp = (p == 0) ? ga.outQ : (p == 1) ? ga.outK : ga.outV;
    if (p == 2) {
      #pragma unroll
      for (int r = 0; r < 4; ++r)
        #pragma unroll
        for (int c = 0; c < 16; ++c)
          outp[(size_t)(rowBase + ty*4 + r)*C_ + tx + 16*c] = acc[r][c];
    } else {
      __syncthreads();
      float* red = &xs[0][0];
      float* rnorm = &wsm[0][0];
      #pragma unroll
      for (int r = 0; r < 4; ++r) red[(ty*4 + r)*17 + tx] = part[r];
      __syncthreads();
      if (tid < 64) {
        float s = 0.f;
        #pragma unroll
        for (int i = 0; i < 16; ++i) s += red[tid*17 + i];
        rnorm[tid] = 1.f / (sqrtf(s) + 1e-6f);
      }
      __syncthreads();
      #pragma unroll
      for (int r = 0; r < 4; ++r) {
        float sc = rnorm[ty*4 + r];
        #pragma unroll
        for (int c = 0; c < 16; ++c)
          outp[(size_t)(rowBase + ty*4 + r)*C_ + tx + 16*c] = acc[r][c] * sc;
      }
    }
  } else if (p <= 4) {
    float part[4] = {0.f, 0.f, 0.f, 0.f};
    #pragma unroll
    for (int r = 0; r < 4; ++r)
      #pragma unroll
      for (int c = 0; c < 16; ++c) {
        float y = acc[r][c];
        part[r] += 1.f / (1.f + __expf(-y));
      }
    __syncthreads();
    float* red = &xs[0][0];
    #pragma unroll
    for (int r = 0; r < 4; ++r) red[(ty*4 + r)*17 + tx] = part[r];
    __syncthreads();
    if (tid < 64) {
      float s = 0.f;
      #pragma unroll
      for (int i = 0; i < 16; ++i) s += red[tid*17 + i];
      ((p == 3) ? ga.outA : ga.outB)[rowBase + tid] = s * (1.f / 256.f);
    }
  } else {
    #pragma unroll
    for (int r = 0; r < 4; ++r)
      #pragma unroll
      for (int c = 0; c < 16; ++c)
        ga.outO[(size_t)(rowBase + ty*4 + r)*C_ + tx + 16*c] = acc[r][c];
  }
}

// ---------------- fused gram + WY solves + intra output (R14 verbatim) -----
__global__ __launch_bounds__(256) void chunk_prep(const float* __restrict__ kn,
                                                  const float* __restrict__ qn,
                                                  float* __restrict__ vO,
                                                  const float* __restrict__ Ag,
                                                  const float* __restrict__ Bg,
                                                  float* __restrict__ Ubuf,
                                                  float* __restrict__ qrm,
                                                  float* __restrict__ gbuf,
                                                  float* __restrict__ Oout) {
  __shared__ float Gl[64][68];
  __shared__ float Wl[64][68];
  __shared__ float pool[17408];       // gram: Kp+Qp; solves: UY rows [j*68]
  __shared__ float gam[64], al[64], bl[64];
  float* Kp = pool;
  float* Qp = pool + 4096;
  const int bid = blockIdx.x;
  const int b = bid & 7, c = bid >> 3;
  const size_t ct0 = (size_t)b*N_ + (size_t)c*T_;
  const size_t base = ct0 * C_;
  const int tid = threadIdx.x;
  const int lane = tid & 63;
  const int sg = tid >> 6;

  if (tid < 64) { al[tid] = Ag[ct0 + tid]; bl[tid] = Bg[ct0 + tid]; }

  float accG[16], accQ[16];
  #pragma unroll
  for (int m = 0; m < 16; ++m) { accG[m] = 0.f; accQ[m] = 0.f; }
  for (int p = 0; p < 4; ++p) {
    __syncthreads();
    #pragma unroll
    for (int i = 0; i < 4; ++i) {
      int idx = i*256 + tid;
      int t = idx >> 4, u = idx & 15;
      int phys = (t*16 + (u ^ (t & 15))) * 4;
      *(float4*)&Kp[phys] = *(const float4*)(kn + base + (size_t)t*C_ + p*64 + u*4);
      *(float4*)&Qp[phys] = *(const float4*)(qn + base + (size_t)t*C_ + p*64 + u*4);
    }
    __syncthreads();
    #pragma unroll 4
    for (int j4 = 0; j4 < 16; ++j4) {
      float4 kt = *(const float4*)&Kp[(lane*16 + (j4 ^ (lane & 15))) * 4];
      float4 qt = *(const float4*)&Qp[(lane*16 + (j4 ^ (lane & 15))) * 4];
      #pragma unroll
      for (int m = 0; m < 16; ++m) {
        int r = sg*16 + m;
        float4 ks = *(const float4*)&Kp[(r*16 + (j4 ^ (r & 15))) * 4];
        accG[m] += dot4(kt, ks);
        accQ[m] += dot4(qt, ks);
      }
    }
  }
  __syncthreads();
  #pragma unroll
  for (int m = 0; m < 16; ++m) {
    int col = sg*16 + m;
    Gl[lane][col] = (col <  lane) ? accG[m] : 0.f;
    Wl[lane][col] = (col <= lane) ? accQ[m] : 0.f;
  }
  __syncthreads();
  if (tid == 0) {
    float g = 1.f;
    for (int s = 0; s < 64; ++s) { g *= al[s]; gam[s] = g; }
  }
  __syncthreads();
  if (tid < 64) gbuf[ct0 + tid] = gam[tid];
  __syncthreads();

  const int j = tid;
  float* const myrow = &pool[j * 68];

  for (int s = 0; s < 64; ++s) {
    float a0 = kn[base + (size_t)s*C_ + j], a1 = 0.f, a2 = 0.f, a3 = 0.f;
    for (int r4 = 0; r4 <= (s >> 2); ++r4) {
      float4 g = *(const float4*)&Gl[s][r4*4];
      float4 uu = *(const float4*)&myrow[r4*4];
      a0 -= g.x*uu.x; a1 -= g.y*uu.y; a2 -= g.z*uu.z; a3 -= g.w*uu.w;
    }
    float us = bl[s] * ((a0 + a1) + (a2 + a3));
    myrow[s] = us;
    Ubuf[base + (size_t)s*C_ + j] = us;
  }

  for (int t = 0; t < 64; ++t) {
    float a0 = qn[base + (size_t)t*C_ + j], a1 = 0.f, a2 = 0.f, a3 = 0.f;
    for (int s4 = 0; s4 < 16; ++s4) {
      float4 w = *(const float4*)&Wl[t][s4*4];
      float4 uu = *(const float4*)&myrow[s4*4];
      a0 -= w.x*uu.x; a1 -= w.y*uu.y; a2 -= w.z*uu.z; a3 -= w.w*uu.w;
    }
    qrm[base + (size_t)t*C_ + j] = (a0 + a1) + (a2 + a3);
  }

  __syncthreads();
  #pragma unroll
  for (int p2 = 0; p2 < 16; ++p2) {
    int idx = p2*256 + tid; int s = idx >> 6, r = idx & 63;
    float rs = gam[s] / gam[r];
    Gl[s][r] *= rs;
    Wl[s][r] *= rs;
  }
  __syncthreads();
  const float gT = gam[63];

  for (int s = 0; s < 64; ++s) {
    float a0 = vO[base + (size_t)s*C_ + j], a1 = 0.f, a2 = 0.f, a3 = 0.f;
    for (int r4 = 0; r4 <= (s >> 2); ++r4) {
      float4 g = *(const float4*)&Gl[s][r4*4];
      float4 yy = *(const float4*)&myrow[r4*4];
      a0 -= g.x*yy.x; a1 -= g.y*yy.y; a2 -= g.z*yy.z; a3 -= g.w*yy.w;
    }
    myrow[s] = bl[s] * ((a0 + a1) + (a2 + a3));
  }
  __syncthreads();
  for (int s4 = 0; s4 < 16; ++s4) {
    float4 yy = *(const float4*)&myrow[s4*4];
    float z0 = (gT / gam[s4*4+0]) * yy.x;
    float z1 = (gT / gam[s4*4+1]) * yy.y;
    float z2 = (gT / gam[s4*4+2]) * yy.z;
    float z3 = (gT / gam[s4*4+3]) * yy.w;
    *(float4*)&vO[base + (size_t)j*64 + s4*4] = make_float4(z0, z1, z2, z3);  // Z^T [i][s]
  }
  for (int t = 0; t < 64; ++t) {
    float a0 = 0.f, a1 = 0.f, a2 = 0.f, a3 = 0.f;
    for (int s4 = 0; s4 < 16; ++s4) {
      float4 w = *(const float4*)&Wl[t][s4*4];
      float4 yy = *(const float4*)&myrow[s4*4];
      a0 += w.x*yy.x; a1 += w.y*yy.y; a2 += w.z*yy.z; a3 += w.w*yy.w;
    }
    Oout[base + (size_t)t*C_ + j] = (a0 + a1) + (a2 + a3);
  }
}

// ---------------- serial chunk scan v3: j-split across waves ---------------
// grid 256 = (b = bid&7, wgrp = bid>>3); WG = 256 threads = 4 waves; WG owns
// 8 S-rows (i0 = wgrp*8). Wave w owns j-quarter [64w, 64w+64): lane l holds
// S[r][64w+l] for r=0..7 (8 VGPRs). Pass A+B: each wave reads ONLY its
// quarter of the Q~/U tiles (per-CU A+B LDS reads drop 4x vs R14), partial
// oA/dB reduced across waves via padded LDS. Pass C: lane reads K[s][64w+l]
// b32 (conflict-free), cf broadcast by readlane. Wave 0 does the O RMW.
__global__ __launch_bounds__(256) void chunk_scan(const float* __restrict__ kn,
                                                  const float* __restrict__ qrm,
                                                  const float* __restrict__ urm,
                                                  const float* __restrict__ ztT,
                                                  const float* __restrict__ gbuf,
                                                  float* __restrict__ Oout) {
  __shared__ float Qs[16384];   // swizzled Q~ rows, later linear K
  __shared__ float Us[16384];   // swizzled U rows
  __shared__ float red[4*64*20];// partial oA/dB: [w][lane][16 used of 20]
  const int bid = blockIdx.x;
  const int b = bid & 7;
  const int wgrp = bid >> 3;
  const int tid = threadIdx.x;
  const int wave = tid >> 6, lane = tid & 63;
  const int i0 = wgrp*8;
  const int lx = lane & 15;     // swizzle key (lane = t in A+B reads)

  float S_[8];
  #pragma unroll
  for (int r = 0; r < 8; ++r) S_[r] = 0.f;

  for (int ch = 0; ch < NCH; ++ch) {
    const size_t ct0 = (size_t)b*N_ + (size_t)ch*T_;
    const size_t base = ct0 * C_;

    // stage Q~/U row-major, 16B XOR swizzle (unit u of row t -> u^(t&15))
    #pragma unroll
    for (int i = 0; i < 16; ++i) {
      int g = i*256 + tid;
      int t = g >> 6, u = g & 63;
      int phys = (t*64 + (u ^ (t & 15))) * 4;
      *(float4*)&Qs[phys] = *(const float4*)(qrm + base + (size_t)g*4);
      *(float4*)&Us[phys] = *(const float4*)(urm + base + (size_t)g*4);
    }
    __syncthreads();                               // B1

    const float gv = gbuf[ct0 + lane];
    const float gT = rdlane(gv, 63);

    // Pass A+B partials over this wave's j-quarter (lane = t = s)
    float oA[8], dB[8];
    #pragma unroll
    for (int r = 0; r < 8; ++r) { oA[r] = 0.f; dB[r] = 0.f; }
    #pragma unroll
    for (int uu = 0; uu < 16; ++uu) {
      const int u = (wave << 4) + uu;              // logical 16B unit
      float4 qv = *(const float4*)&Qs[(lane*64 + (u ^ lx)) * 4];
      float4 uv = *(const float4*)&Us[(lane*64 + (u ^ lx)) * 4];
      #pragma unroll
      for (int m = 0; m < 4; ++m) {
        const int jl = 4*uu + m;                   // j_local in quarter
        const float qm = (m==0) ? qv.x : (m==1) ? qv.y : (m==2) ? qv.z : qv.w;
        const float um = (m==0) ? uv.x : (m==1) ? uv.y : (m==2) ? uv.z : uv.w;
        #pragma unroll
        for (int r = 0; r < 8; ++r) {
          const float sv = rdlane(S_[r], jl);
          oA[r] += sv * qm;
          dB[r] += sv * um;
        }
      }
    }
    // write partials
    {
      float* rp = &red[(wave*64 + lane) * 20];
      *(float4*)&rp[0]  = make_float4(oA[0], oA[1], oA[2], oA[3]);
      *(float4*)&rp[4]  = make_float4(oA[4], oA[5], oA[6], oA[7]);
      *(float4*)&rp[8]  = make_float4(dB[0], dB[1], dB[2], dB[3]);
      *(float4*)&rp[12] = make_float4(dB[4], dB[5], dB[6], dB[7]);
    }
    __syncthreads();                               // B2 (red ready; Qs reads done)

    // restage K (row-major linear) over the Qs region
    #pragma unroll
    for (int i = 0; i < 16; ++i) {
      int idx = (i*256 + tid) * 4;
      *(float4*)&Qs[idx] = *(const float4*)(kn + base + idx);
    }

    // cross-wave reduce
    #pragma unroll
    for (int r = 0; r < 8; ++r) { oA[r] = 0.f; dB[r] = 0.f; }
    #pragma unroll
    for (int w2 = 0; w2 < 4; ++w2) {
      const float* rp = &red[(w2*64 + lane) * 20];
      float4 a = *(const float4*)&rp[0];
      float4 bq = *(const float4*)&rp[4];
      float4 cq = *(const float4*)&rp[8];
      float4 dq = *(const float4*)&rp[12];
      oA[0] += a.x;  oA[1] += a.y;  oA[2] += a.z;  oA[3] += a.w;
      oA[4] += bq.x; oA[5] += bq.y; oA[6] += bq.z; oA[7] += bq.w;
      dB[0] += cq.x; dB[1] += cq.y; dB[2] += cq.z; dB[3] += cq.w;
      dB[4] += dq.x; dB[5] += dq.y; dB[6] += dq.z; dB[7] += dq.w;
    }
    // cf[s=lane][r] = gT*dB - Z ; reuse dB registers
    #pragma unroll
    for (int r = 0; r < 8; ++r) {
      const float z = ztT[base + (size_t)(i0 + r)*64 + lane];
      dB[r] = gT*dB[r] - z;
    }
    // O RMW: only wave 0 (single writer per element)
    if (wave == 0) {
      float* orow = Oout + base + (size_t)lane*C_ + i0;
      float4 o0 = *(float4*)&orow[0];
      float4 o1 = *(float4*)&orow[4];
      o0.x += gv*oA[0]; o0.y += gv*oA[1]; o0.z += gv*oA[2]; o0.w += gv*oA[3];
      o1.x += gv*oA[4]; o1.y += gv*oA[5]; o1.z += gv*oA[6]; o1.w += gv*oA[7];
      *(float4*)&orow[0] = o0;
      *(float4*)&orow[4] = o1;
    }
    __syncthreads();                               // B3 (K staged; red reads done)

    // Pass C: S'[r][j] = gT*S - sum_s cf[s][r]*K[s][j]; lane j = 64w+lane
    float acc[8];
    #pragma unroll
    for (int r = 0; r < 8; ++r) acc[r] = 0.f;
    const int jcol = (wave << 6) + lane;
    #pragma unroll 8
    for (int s = 0; s < 64; ++s) {
      const float kv = Qs[s*256 + jcol];
      #pragma unroll
      for (int r = 0; r < 8; ++r)
        acc[r] += rdlane(dB[r], s) * kv;
    }
    #pragma unroll
    for (int r = 0; r < 8; ++r) S_[r] = gT*S_[r] - acc[r];
    __syncthreads();                               // B4 (C reads done)
  }
}

extern "C" void kernel_launch(void* const* d_in, const int* in_sizes, int n_in,
                              void* d_out, int out_size, void* d_ws, size_t ws_size,
                              hipStream_t stream) {
  const float* x  = (const float*)d_in[0];
  const float* Wq = (const float*)d_in[1];  const float* bq = (const float*)d_in[2];
  const float* Wk = (const float*)d_in[3];  const float* bk = (const float*)d_in[4];
  const float* Wv = (const float*)d_in[5];  const float* bv = (const float*)d_in[6];
  const float* Wa = (const float*)d_in[7];  const float* ba = (const float*)d_in[8];
  const float* Wb = (const float*)d_in[9];  const float* bb = (const float*)d_in[10];
  const float* Wo = (const float*)d_in[11]; const float* bo = (const float*)d_in[12];

  float* ws = (float*)d_ws;
  const size_t TC = (size_t)TOK * C_;
  float* qn   = ws;                    // Q projection (read-only after proj)
  float* kn   = ws + TC;
  float* vO   = ws + 2*TC;             // V -> Z^T [i][s] (in place)
  float* Ag   = ws + 3*TC;
  float* Bg   = Ag + TOK;
  float* gbuf = Bg + TOK;
  float* Ubuf = gbuf + TOK;            // U row-major
  float* qrm  = Ubuf + TC;             // Qtilde row-major

  GArgs ga;
  ga.W[0] = Wq; ga.W[1] = Wk; ga.W[2] = Wv; ga.W[3] = Wa; ga.W[4] = Wb; ga.W[5] = Wo;
  ga.bias[0] = bq; ga.bias[1] = bk; ga.bias[2] = bv; ga.bias[3] = ba; ga.bias[4] = bb; ga.bias[5] = bo;
  ga.outQ = qn; ga.outK = kn; ga.outV = vO; ga.outA = Ag; ga.outB = Bg;
  ga.outO = (float*)d_out;

  gemm_multi<<<dim3(TOK/64, 5), 256, 0, stream>>>(x, 0, ga);
  chunk_prep<<<dim3(256), 256, 0, stream>>>(kn, qn, vO, Ag, Bg, Ubuf, qrm, gbuf,
                                            (float*)d_out);
  chunk_scan<<<dim3(256), 256, 0, stream>>>(kn, qrm, Ubuf, vO, gbuf,
                                            (float*)d_out);
  gemm_multi<<<dim3(TOK/64, 1), 256, 0, stream>>>((float*)d_out, 5, ga);
}

// Round 18
// 742.134 us; speedup vs baseline: 1.5346x; 1.0032x over previous
//
#include <hip/hip_runtime.h>
#include <math.h>

#define B_ 8
#define N_ 2048
#define C_ 256
#define TOK (B_*N_)
#define T_ 64
#define NCH (N_/T_)   // 32 chunks per batch

typedef __bf16 bf16x8 __attribute__((ext_vector_type(8)));
typedef float f32x4v __attribute__((ext_vector_type(4)));

struct GArgs {
  const float* W[6];
  const float* bias[6];
  float* outQ; float* outK; float* outV; float* outA; float* outB; float* outO;
};

__device__ __forceinline__ float dot4(const float4& a, const float4& b) {
  return (a.x*b.x + a.y*b.y) + (a.z*b.z + a.w*b.w);
}
__device__ __forceinline__ float rdlane(float x, int idx) {
  return __int_as_float(__builtin_amdgcn_readlane(__float_as_int(x), idx));
}
__device__ __forceinline__ float bf2f(unsigned short u) {
  return __uint_as_float(((unsigned)u) << 16);
}
__device__ __forceinline__ unsigned short f2bf(float f) {
  unsigned x = __float_as_uint(f);
  return (unsigned short)((x + 0x7FFFu + ((x >> 16) & 1u)) >> 16);
}

// ---------------- Tiled f32 GEMM with fused epilogues (R15 verbatim) -------
__global__ __launch_bounds__(256) void gemm_multi(const float* __restrict__ X,
                                                  int pbase, GArgs ga) {
  const int p = pbase + blockIdx.y;
  const float* __restrict__ Wp = ga.W[p];
  const float* __restrict__ bp = ga.bias[p];
  const int rowBase = blockIdx.x * 64;
  const int tid = threadIdx.x;
  const int tx = tid & 15;
  const int ty = tid >> 4;

  __shared__ float xs[64][33];
  __shared__ float wsm[256][33];

  float acc[4][16];
  #pragma unroll
  for (int r = 0; r < 4; ++r)
    #pragma unroll
    for (int c = 0; c < 16; ++c) acc[r][c] = bp[tx + 16*c];

  for (int k0 = 0; k0 < C_; k0 += 32) {
    #pragma unroll
    for (int pass = 0; pass < 2; ++pass) {
      int flat = (pass*256 + tid) * 4;
      int r = flat >> 5, kk = flat & 31;
      const float4 v = *(const float4*)(X + (size_t)(rowBase + r)*C_ + k0 + kk);
      xs[r][kk] = v.x; xs[r][kk+1] = v.y; xs[r][kk+2] = v.z; xs[r][kk+3] = v.w;
    }
    #pragma unroll
    for (int pass = 0; pass < 8; ++pass) {
      int flat = (pass*256 + tid) * 4;
      int c = flat >> 5, kk = flat & 31;
      const float4 v = *(const float4*)(Wp + (size_t)c*C_ + k0 + kk);
      wsm[c][kk] = v.x; wsm[c][kk+1] = v.y; wsm[c][kk+2] = v.z; wsm[c][kk+3] = v.w;
    }
    __syncthreads();
    #pragma unroll
    for (int kk = 0; kk < 32; ++kk) {
      float xr[4];
      #pragma unroll
      for (int r = 0; r < 4; ++r) xr[r] = xs[ty*4 + r][kk];
      #pragma unroll
      for (int c = 0; c < 16; ++c) {
        float wv = wsm[tx + 16*c][kk];
        #pragma unroll
        for (int r = 0; r < 4; ++r) acc[r][c] += xr[r] * wv;
      }
    }
    __syncthreads();
  }

  if (p <= 2) {
    float part[4] = {0.f, 0.f, 0.f, 0.f};
    #pragma unroll
    for (int r = 0; r < 4; ++r)
      #pragma unroll
      for (int c = 0; c < 16; ++c) {
        float y = acc[r][c];
        float s = y / (1.f + __expf(-y));
        acc[r][c] = s;
        part[r] += s * s;
      }
    float* outp = (p == 0) ? ga.outQ : (p == 1) ? ga.outK : ga.outV;
    if (p == 2) {
      #pragma unroll
      for (int r = 0; r < 4; ++r)
        #pragma unroll
        for (int c = 0; c < 16; ++c)
          outp[(size_t)(rowBase + ty*4 + r)*C_ + tx + 16*c] = acc[r][c];
    } else {
      __syncthreads();
      float* red = &xs[0][0];
      float* rnorm = &wsm[0][0];
      #pragma unroll
      for (int r = 0; r < 4; ++r) red[(ty*4 + r)*17 + tx] = part[r];
      __syncthreads();
      if (tid < 64) {
        float s = 0.f;
        #pragma unroll
        for (int i = 0; i < 16; ++i) s += red[tid*17 + i];
        rnorm[tid] = 1.f / (sqrtf(s) + 1e-6f);
      }
      __syncthreads();
      #pragma unroll
      for (int r = 0; r < 4; ++r) {
        float sc = rnorm[ty*4 + r];
        #pragma unroll
        for (int c = 0; c < 16; ++c)
          outp[(size_t)(rowBase + ty*4 + r)*C_ + tx + 16*c] = acc[r][c] * sc;
      }
    }
  } else if (p <= 4) {
    float part[4] = {0.f, 0.f, 0.f, 0.f};
    #pragma unroll
    for (int r = 0; r < 4; ++r)
      #pragma unroll
      for (int c = 0; c < 16; ++c) {
        float y = acc[r][c];
        part[r] += 1.f / (1.f + __expf(-y));
      }
    __syncthreads();
    float* red = &xs[0][0];
    #pragma unroll
    for (int r = 0; r < 4; ++r) red[(ty*4 + r)*17 + tx] = part[r];
    __syncthreads();
    if (tid < 64) {
      float s = 0.f;
      #pragma unroll
      for (int i = 0; i < 16; ++i) s += red[tid*17 + i];
      ((p == 3) ? ga.outA : ga.outB)[rowBase + tid] = s * (1.f / 256.f);
    }
  } else {
    #pragma unroll
    for (int r = 0; r < 4; ++r)
      #pragma unroll
      for (int c = 0; c < 16; ++c)
        ga.outO[(size_t)(rowBase + ty*4 + r)*C_ + tx + 16*c] = acc[r][c];
  }
}

// ---------------- bf16 hi/lo split (O) -------------------------------------
__global__ __launch_bounds__(256) void split_bf(const float* __restrict__ src,
                                                unsigned short* __restrict__ hi,
                                                unsigned short* __restrict__ lo) {
  const size_t i = ((size_t)blockIdx.x * 256 + threadIdx.x) * 4;
  float4 v = *(const float4*)(src + i);
  ushort4 H, L;
  H.x = f2bf(v.x); H.y = f2bf(v.y); H.z = f2bf(v.z); H.w = f2bf(v.w);
  L.x = f2bf(v.x - bf2f(H.x));
  L.y = f2bf(v.y - bf2f(H.y));
  L.z = f2bf(v.z - bf2f(H.z));
  L.w = f2bf(v.w - bf2f(H.w));
  *(ushort4*)(hi + i) = H;
  *(ushort4*)(lo + i) = L;
}

// ---------------- bf16 hi/lo split for ONE weight matrix -------------------
__global__ __launch_bounds__(256) void split_w1(const float* __restrict__ W,
                                                unsigned short* __restrict__ wh,
                                                unsigned short* __restrict__ wl) {
  const size_t i = ((size_t)blockIdx.x * 256 + threadIdx.x) * 4;
  float4 v = *(const float4*)(W + i);
  ushort4 H, L;
  H.x = f2bf(v.x); H.y = f2bf(v.y); H.z = f2bf(v.z); H.w = f2bf(v.w);
  L.x = f2bf(v.x - bf2f(H.x));
  L.y = f2bf(v.y - bf2f(H.y));
  L.z = f2bf(v.z - bf2f(H.z));
  L.w = f2bf(v.w - bf2f(H.w));
  *(ushort4*)(wh + i) = H;
  *(ushort4*)(wl + i) = L;
}

// ---------------- MFMA final projection: Y = O @ Wo^T + bo (bisect probe) --
// bf16x3 split: y = oh*wh + oh*wl + ol*wh. grid (TOK/64), 4 waves; wave w:
// rows rowBase+w*16..+16 x 256 cols as 16 MFMA 16x16x32 tiles.
// A: lane l = O[rowBase+(l&15)][k0+(l>>4)*8..+8] b128.
// B: lane l = Wo[nt*16+(l&15)][same k] b128.
// C/D assumed: lane l, reg e -> row (l>>4)*4+e, col (l&15).
// If this is transposed, absmax will be LARGE-FINITE (diagnostic), not NaN.
__global__ __launch_bounds__(256) void proj_mfma5(const unsigned short* __restrict__ oh,
                                                  const unsigned short* __restrict__ ol,
                                                  const unsigned short* __restrict__ wh,
                                                  const unsigned short* __restrict__ wl,
                                                  const float* __restrict__ bo,
                                                  float* __restrict__ out) {
  const int tid = threadIdx.x;
  const int l = tid & 63, w = tid >> 6;
  const int lc = l & 15, kg = l >> 4;
  const int rowBase = blockIdx.x * 64 + w * 16;
  const unsigned short* ohp = oh + (size_t)(rowBase + lc) * C_;
  const unsigned short* olp = ol + (size_t)(rowBase + lc) * C_;

  f32x4v acc[16];
  #pragma unroll
  for (int nt = 0; nt < 16; ++nt) acc[nt] = (f32x4v){0.f, 0.f, 0.f, 0.f};

  for (int k0 = 0; k0 < C_; k0 += 32) {
    const int ko = k0 + kg * 8;
    bf16x8 ah = *reinterpret_cast<const bf16x8*>(ohp + ko);
    bf16x8 al = *reinterpret_cast<const bf16x8*>(olp + ko);
    #pragma unroll
    for (int nt = 0; nt < 16; ++nt) {
      const size_t wo = (size_t)(nt * 16 + lc) * C_ + ko;
      bf16x8 bh = *reinterpret_cast<const bf16x8*>(wh + wo);
      bf16x8 bl = *reinterpret_cast<const bf16x8*>(wl + wo);
      acc[nt] = __builtin_amdgcn_mfma_f32_16x16x32_bf16(ah, bh, acc[nt], 0, 0, 0);
      acc[nt] = __builtin_amdgcn_mfma_f32_16x16x32_bf16(ah, bl, acc[nt], 0, 0, 0);
      acc[nt] = __builtin_amdgcn_mfma_f32_16x16x32_bf16(al, bh, acc[nt], 0, 0, 0);
    }
  }

  const int orow = rowBase + kg*4;
  #pragma unroll
  for (int nt = 0; nt < 16; ++nt) {
    const float bval = bo[nt*16 + lc];
    #pragma unroll
    for (int e = 0; e < 4; ++e)
      out[(size_t)(orow + e)*C_ + nt*16 + lc] = acc[nt][e] + bval;
  }
}

// ---------------- fused gram + WY solves + intra output (R15 verbatim) -----
__global__ __launch_bounds__(256) void chunk_prep(const float* __restrict__ kn,
                                                  const float* __restrict__ qn,
                                                  float* __restrict__ vO,
                                                  const float* __restrict__ Ag,
                                                  const float* __restrict__ Bg,
                                                  float* __restrict__ Ubuf,
                                                  float* __restrict__ qrm,
                                                  float* __restrict__ gbuf,
                                                  float* __restrict__ Oout) {
  __shared__ float Gl[64][68];
  __shared__ float Wl[64][68];
  __shared__ float pool[17408];
  __shared__ float gam[64], al[64], bl[64];
  float* Kp = pool;
  float* Qp = pool + 4096;
  const int bid = blockIdx.x;
  const int b = bid & 7, c = bid >> 3;
  const size_t ct0 = (size_t)b*N_ + (size_t)c*T_;
  const size_t base = ct0 * C_;
  const int tid = threadIdx.x;
  const int lane = tid & 63;
  const int sg = tid >> 6;

  if (tid < 64) { al[tid] = Ag[ct0 + tid]; bl[tid] = Bg[ct0 + tid]; }

  float accG[16], accQ[16];
  #pragma unroll
  for (int m = 0; m < 16; ++m) { accG[m] = 0.f; accQ[m] = 0.f; }
  for (int p = 0; p < 4; ++p) {
    __syncthreads();
    #pragma unroll
    for (int i = 0; i < 4; ++i) {
      int idx = i*256 + tid;
      int t = idx >> 4, u = idx & 15;
      int phys = (t*16 + (u ^ (t & 15))) * 4;
      *(float4*)&Kp[phys] = *(const float4*)(kn + base + (size_t)t*C_ + p*64 + u*4);
      *(float4*)&Qp[phys] = *(const float4*)(qn + base + (size_t)t*C_ + p*64 + u*4);
    }
    __syncthreads();
    #pragma unroll 4
    for (int j4 = 0; j4 < 16; ++j4) {
      float4 kt = *(const float4*)&Kp[(lane*16 + (j4 ^ (lane & 15))) * 4];
      float4 qt = *(const float4*)&Qp[(lane*16 + (j4 ^ (lane & 15))) * 4];
      #pragma unroll
      for (int m = 0; m < 16; ++m) {
        int r = sg*16 + m;
        float4 ks = *(const float4*)&Kp[(r*16 + (j4 ^ (r & 15))) * 4];
        accG[m] += dot4(kt, ks);
        accQ[m] += dot4(qt, ks);
      }
    }
  }
  __syncthreads();
  #pragma unroll
  for (int m = 0; m < 16; ++m) {
    int col = sg*16 + m;
    Gl[lane][col] = (col <  lane) ? accG[m] : 0.f;
    Wl[lane][col] = (col <= lane) ? accQ[m] : 0.f;
  }
  __syncthreads();
  if (tid == 0) {
    float g = 1.f;
    for (int s = 0; s < 64; ++s) { g *= al[s]; gam[s] = g; }
  }
  __syncthreads();
  if (tid < 64) gbuf[ct0 + tid] = gam[tid];
  __syncthreads();

  const int j = tid;
  float* const myrow = &pool[j * 68];

  for (int s = 0; s < 64; ++s) {
    float a0 = kn[base + (size_t)s*C_ + j], a1 = 0.f, a2 = 0.f, a3 = 0.f;
    for (int r4 = 0; r4 <= (s >> 2); ++r4) {
      float4 g = *(const float4*)&Gl[s][r4*4];
      float4 uu = *(const float4*)&myrow[r4*4];
      a0 -= g.x*uu.x; a1 -= g.y*uu.y; a2 -= g.z*uu.z; a3 -= g.w*uu.w;
    }
    float us = bl[s] * ((a0 + a1) + (a2 + a3));
    myrow[s] = us;
    Ubuf[base + (size_t)s*C_ + j] = us;
  }

  for (int t = 0; t < 64; ++t) {
    float a0 = qn[base + (size_t)t*C_ + j], a1 = 0.f, a2 = 0.f, a3 = 0.f;
    for (int s4 = 0; s4 < 16; ++s4) {
      float4 w = *(const float4*)&Wl[t][s4*4];
      float4 uu = *(const float4*)&myrow[s4*4];
      a0 -= w.x*uu.x; a1 -= w.y*uu.y; a2 -= w.z*uu.z; a3 -= w.w*uu.w;
    }
    qrm[base + (size_t)t*C_ + j] = (a0 + a1) + (a2 + a3);
  }

  __syncthreads();
  #pragma unroll
  for (int p2 = 0; p2 < 16; ++p2) {
    int idx = p2*256 + tid; int s = idx >> 6, r = idx & 63;
    float rs = gam[s] / gam[r];
    Gl[s][r] *= rs;
    Wl[s][r] *= rs;
  }
  __syncthreads();
  const float gT = gam[63];

  for (int s = 0; s < 64; ++s) {
    float a0 = vO[base + (size_t)s*C_ + j], a1 = 0.f, a2 = 0.f, a3 = 0.f;
    for (int r4 = 0; r4 <= (s >> 2); ++r4) {
      float4 g = *(const float4*)&Gl[s][r4*4];
      float4 yy = *(const float4*)&myrow[r4*4];
      a0 -= g.x*yy.x; a1 -= g.y*yy.y; a2 -= g.z*yy.z; a3 -= g.w*yy.w;
    }
    myrow[s] = bl[s] * ((a0 + a1) + (a2 + a3));
  }
  __syncthreads();
  for (int s4 = 0; s4 < 16; ++s4) {
    float4 yy = *(const float4*)&myrow[s4*4];
    float z0 = (gT / gam[s4*4+0]) * yy.x;
    float z1 = (gT / gam[s4*4+1]) * yy.y;
    float z2 = (gT / gam[s4*4+2]) * yy.z;
    float z3 = (gT / gam[s4*4+3]) * yy.w;
    *(float4*)&vO[base + (size_t)j*64 + s4*4] = make_float4(z0, z1, z2, z3);
  }
  for (int t = 0; t < 64; ++t) {
    float a0 = 0.f, a1 = 0.f, a2 = 0.f, a3 = 0.f;
    for (int s4 = 0; s4 < 16; ++s4) {
      float4 w = *(const float4*)&Wl[t][s4*4];
      float4 yy = *(const float4*)&myrow[s4*4];
      a0 += w.x*yy.x; a1 += w.y*yy.y; a2 += w.z*yy.z; a3 += w.w*yy.w;
    }
    Oout[base + (size_t)t*C_ + j] = (a0 + a1) + (a2 + a3);
  }
}

// ---------------- serial chunk scan (R15 verbatim) -------------------------
__global__ __launch_bounds__(256) void chunk_scan(const float* __restrict__ kn,
                                                  const float* __restrict__ qrm,
                                                  const float* __restrict__ urm,
                                                  const float* __restrict__ ztT,
                                                  const float* __restrict__ gbuf,
                                                  float* __restrict__ Oout) {
  __shared__ float Qs[16384];
  __shared__ float Us[16384];
  __shared__ float red[4*64*20];
  const int bid = blockIdx.x;
  const int b = bid & 7;
  const int wgrp = bid >> 3;
  const int tid = threadIdx.x;
  const int wave = tid >> 6, lane = tid & 63;
  const int i0 = wgrp*8;
  const int lx = lane & 15;

  float S_[8];
  #pragma unroll
  for (int r = 0; r < 8; ++r) S_[r] = 0.f;

  for (int ch = 0; ch < NCH; ++ch) {
    const size_t ct0 = (size_t)b*N_ + (size_t)ch*T_;
    const size_t base = ct0 * C_;

    #pragma unroll
    for (int i = 0; i < 16; ++i) {
      int g = i*256 + tid;
      int t = g >> 6, u = g & 63;
      int phys = (t*64 + (u ^ (t & 15))) * 4;
      *(float4*)&Qs[phys] = *(const float4*)(qrm + base + (size_t)g*4);
      *(float4*)&Us[phys] = *(const float4*)(urm + base + (size_t)g*4);
    }
    __syncthreads();                               // B1

    const float gv = gbuf[ct0 + lane];
    const float gT = rdlane(gv, 63);

    float oA[8], dB[8];
    #pragma unroll
    for (int r = 0; r < 8; ++r) { oA[r] = 0.f; dB[r] = 0.f; }
    #pragma unroll
    for (int uu = 0; uu < 16; ++uu) {
      const int u = (wave << 4) + uu;
      float4 qv = *(const float4*)&Qs[(lane*64 + (u ^ lx)) * 4];
      float4 uv = *(const float4*)&Us[(lane*64 + (u ^ lx)) * 4];
      #pragma unroll
      for (int m = 0; m < 4; ++m) {
        const int jl = 4*uu + m;
        const float qm = (m==0) ? qv.x : (m==1) ? qv.y : (m==2) ? qv.z : qv.w;
        const float um = (m==0) ? uv.x : (m==1) ? uv.y : (m==2) ? uv.z : uv.w;
        #pragma unroll
        for (int r = 0; r < 8; ++r) {
          const float sv = rdlane(S_[r], jl);
          oA[r] += sv * qm;
          dB[r] += sv * um;
        }
      }
    }
    {
      float* rp = &red[(wave*64 + lane) * 20];
      *(float4*)&rp[0]  = make_float4(oA[0], oA[1], oA[2], oA[3]);
      *(float4*)&rp[4]  = make_float4(oA[4], oA[5], oA[6], oA[7]);
      *(float4*)&rp[8]  = make_float4(dB[0], dB[1], dB[2], dB[3]);
      *(float4*)&rp[12] = make_float4(dB[4], dB[5], dB[6], dB[7]);
    }
    __syncthreads();                               // B2

    #pragma unroll
    for (int i = 0; i < 16; ++i) {
      int idx = (i*256 + tid) * 4;
      *(float4*)&Qs[idx] = *(const float4*)(kn + base + idx);
    }

    #pragma unroll
    for (int r = 0; r < 8; ++r) { oA[r] = 0.f; dB[r] = 0.f; }
    #pragma unroll
    for (int w2 = 0; w2 < 4; ++w2) {
      const float* rp = &red[(w2*64 + lane) * 20];
      float4 a = *(const float4*)&rp[0];
      float4 bq = *(const float4*)&rp[4];
      float4 cq = *(const float4*)&rp[8];
      float4 dq = *(const float4*)&rp[12];
      oA[0] += a.x;  oA[1] += a.y;  oA[2] += a.z;  oA[3] += a.w;
      oA[4] += bq.x; oA[5] += bq.y; oA[6] += bq.z; oA[7] += bq.w;
      dB[0] += cq.x; dB[1] += cq.y; dB[2] += cq.z; dB[3] += cq.w;
      dB[4] += dq.x; dB[5] += dq.y; dB[6] += dq.z; dB[7] += dq.w;
    }
    #pragma unroll
    for (int r = 0; r < 8; ++r) {
      const float z = ztT[base + (size_t)(i0 + r)*64 + lane];
      dB[r] = gT*dB[r] - z;
    }
    if (wave == 0) {
      float* orow = Oout + base + (size_t)lane*C_ + i0;
      float4 o0 = *(float4*)&orow[0];
      float4 o1 = *(float4*)&orow[4];
      o0.x += gv*oA[0]; o0.y += gv*oA[1]; o0.z += gv*oA[2]; o0.w += gv*oA[3];
      o1.x += gv*oA[4]; o1.y += gv*oA[5]; o1.z += gv*oA[6]; o1.w += gv*oA[7];
      *(float4*)&orow[0] = o0;
      *(float4*)&orow[4] = o1;
    }
    __syncthreads();                               // B3

    float acc[8];
    #pragma unroll
    for (int r = 0; r < 8; ++r) acc[r] = 0.f;
    const int jcol = (wave << 6) + lane;
    #pragma unroll 8
    for (int s = 0; s < 64; ++s) {
      const float kv = Qs[s*256 + jcol];
      #pragma unroll
      for (int r = 0; r < 8; ++r)
        acc[r] += rdlane(dB[r], s) * kv;
    }
    #pragma unroll
    for (int r = 0; r < 8; ++r) S_[r] = gT*S_[r] - acc[r];
    __syncthreads();                               // B4
  }
}

extern "C" void kernel_launch(void* const* d_in, const int* in_sizes, int n_in,
                              void* d_out, int out_size, void* d_ws, size_t ws_size,
                              hipStream_t stream) {
  const float* x  = (const float*)d_in[0];
  const float* Wq = (const float*)d_in[1];  const float* bq = (const float*)d_in[2];
  const float* Wk = (const float*)d_in[3];  const float* bk = (const float*)d_in[4];
  const float* Wv = (const float*)d_in[5];  const float* bv = (const float*)d_in[6];
  const float* Wa = (const float*)d_in[7];  const float* ba = (const float*)d_in[8];
  const float* Wb = (const float*)d_in[9];  const float* bb = (const float*)d_in[10];
  const float* Wo = (const float*)d_in[11]; const float* bo = (const float*)d_in[12];

  float* ws = (float*)d_ws;
  const size_t TC = (size_t)TOK * C_;
  float* qn   = ws;                    // Q projection
  float* kn   = ws + TC;
  float* vO   = ws + 2*TC;             // V -> Z^T [i][s] (in place)
  float* Ag   = ws + 3*TC;
  float* Bg   = Ag + TOK;
  float* gbuf = Bg + TOK;
  float* Ubuf = gbuf + TOK;            // U row-major; after scan: Wo splits
  float* qrm  = Ubuf + TC;             // Qtilde row-major; after scan: O splits
  // footprint identical to R15 (proven): 5*TC + 3*TOK floats

  unsigned short* whi = (unsigned short*)Ubuf;     // 65536 ushorts
  unsigned short* wlo = whi + 65536;
  unsigned short* ohi = (unsigned short*)qrm;      // TC ushorts
  unsigned short* olo = ohi + TC;

  GArgs ga;
  ga.W[0] = Wq; ga.W[1] = Wk; ga.W[2] = Wv; ga.W[3] = Wa; ga.W[4] = Wb; ga.W[5] = Wo;
  ga.bias[0] = bq; ga.bias[1] = bk; ga.bias[2] = bv; ga.bias[3] = ba; ga.bias[4] = bb; ga.bias[5] = bo;
  ga.outQ = qn; ga.outK = kn; ga.outV = vO; ga.outA = Ag; ga.outB = Bg;
  ga.outO = (float*)d_out;

  gemm_multi<<<dim3(TOK/64, 5), 256, 0, stream>>>(x, 0, ga);
  chunk_prep<<<dim3(256), 256, 0, stream>>>(kn, qn, vO, Ag, Bg, Ubuf, qrm, gbuf,
                                            (float*)d_out);
  chunk_scan<<<dim3(256), 256, 0, stream>>>(kn, qrm, Ubuf, vO, gbuf,
                                            (float*)d_out);
  split_w1<<<dim3(64), 256, 0, stream>>>(Wo, whi, wlo);          // into Ubuf (dead)
  split_bf<<<dim3(TC/1024), 256, 0, stream>>>((const float*)d_out, ohi, olo);  // into qrm (dead)
  proj_mfma5<<<dim3(TOK/64), 256, 0, stream>>>(ohi, olo, whi, wlo, bo,
                                               (float*)d_out);
}